// Round 6
// baseline (632.033 us; speedup 1.0000x reference)
//
#include <hip/hip_runtime.h>

#define L_SEQ 4096
#define NSTEP 2047
#define ST_W  (-0.000625f)   // -LR * (2/H) = -0.01/16

// ws layout (bytes):
//  [0,      8192)   table  64x32 f32
//  [8192,  24576)   G      64x64 f32
//  [24576, 26624)   Z0     64x8  f32
//  [26624, 26628)   wacc   f32

// ---------------------------------------------------------------------------
// Cross-lane reduction helpers (VALU pipe). Layout: i = lane&7, g = lane>>3.
// ---------------------------------------------------------------------------
__device__ __forceinline__ void redi4(float& a, float& b, float& c, float& d) {
    asm volatile(
        "s_nop 1\n\t"
        "v_add_f32_dpp %0, %0, %0 quad_perm:[1,0,3,2] row_mask:0xf bank_mask:0xf bound_ctrl:0\n\t"
        "v_add_f32_dpp %1, %1, %1 quad_perm:[1,0,3,2] row_mask:0xf bank_mask:0xf bound_ctrl:0\n\t"
        "v_add_f32_dpp %2, %2, %2 quad_perm:[1,0,3,2] row_mask:0xf bank_mask:0xf bound_ctrl:0\n\t"
        "v_add_f32_dpp %3, %3, %3 quad_perm:[1,0,3,2] row_mask:0xf bank_mask:0xf bound_ctrl:0\n\t"
        "v_add_f32_dpp %0, %0, %0 quad_perm:[2,3,0,1] row_mask:0xf bank_mask:0xf bound_ctrl:0\n\t"
        "v_add_f32_dpp %1, %1, %1 quad_perm:[2,3,0,1] row_mask:0xf bank_mask:0xf bound_ctrl:0\n\t"
        "v_add_f32_dpp %2, %2, %2 quad_perm:[2,3,0,1] row_mask:0xf bank_mask:0xf bound_ctrl:0\n\t"
        "v_add_f32_dpp %3, %3, %3 quad_perm:[2,3,0,1] row_mask:0xf bank_mask:0xf bound_ctrl:0\n\t"
        "v_add_f32_dpp %0, %0, %0 row_half_mirror row_mask:0xf bank_mask:0xf bound_ctrl:0\n\t"
        "v_add_f32_dpp %1, %1, %1 row_half_mirror row_mask:0xf bank_mask:0xf bound_ctrl:0\n\t"
        "v_add_f32_dpp %2, %2, %2 row_half_mirror row_mask:0xf bank_mask:0xf bound_ctrl:0\n\t"
        "v_add_f32_dpp %3, %3, %3 row_half_mirror row_mask:0xf bank_mask:0xf bound_ctrl:0"
        : "+v"(a), "+v"(b), "+v"(c), "+v"(d));
}

__device__ __forceinline__ float redg1(float x) {
    float t;
    asm volatile(
        "s_nop 1\n\t"
        "v_add_f32_dpp %0, %0, %0 row_ror:8 row_mask:0xf bank_mask:0xf bound_ctrl:0\n\t"
        "s_nop 1\n\t"
        "v_mov_b32 %1, %0\n\t"
        "s_nop 1\n\t"
        "v_permlane16_swap_b32 %1, %0\n\t"
        "s_nop 0\n\t"
        "v_add_f32 %0, %0, %1\n\t"
        "s_nop 1\n\t"
        "v_mov_b32 %1, %0\n\t"
        "s_nop 1\n\t"
        "v_permlane32_swap_b32 %1, %0\n\t"
        "s_nop 0\n\t"
        "v_add_f32 %0, %0, %1"
        : "+v"(x), "=&v"(t));
    return x;
}

// select Z[r] among 8 regs; r wave-uniform, forced into VGPR -> v_cndmask form
__device__ __forceinline__ float sel8d(const float* Z, int r) {
    int rv;
    asm("v_mov_b32 %0, %1" : "=v"(rv) : "s"(r));
    float a0 = (rv & 1) ? Z[1] : Z[0];
    float a1 = (rv & 1) ? Z[3] : Z[2];
    float a2 = (rv & 1) ? Z[5] : Z[4];
    float a3 = (rv & 1) ? Z[7] : Z[6];
    float b0 = (rv & 2) ? a1 : a0;
    float b1_ = (rv & 2) ? a3 : a2;
    return (rv & 4) ? b1_ : b0;
}

__device__ __forceinline__ float bperm_row(int tok, int i4, float v) {
    int addr = ((tok & 56) << 2) | i4;
    return __int_as_float(__builtin_amdgcn_ds_bpermute(addr, __float_as_int(v)));
}

__device__ __forceinline__ int rli(int x, int l) {
    return __builtin_amdgcn_readlane(x, l);
}
__device__ __forceinline__ float rlf(float x, int l) {
    return __int_as_float(__builtin_amdgcn_readlane(__float_as_int(x), l));
}

// ---------------------------------------------------------------------------
// Phase A: table[v] = LN(e_v + MLP(e_v)); G = table·tableᵀ; Z0 = fc1_w·tableᵀ
// ---------------------------------------------------------------------------
__global__ __launch_bounds__(64) void build_kernel(
    const float* __restrict__ embed, const float* __restrict__ ff1_w,
    const float* __restrict__ ff1_b, const float* __restrict__ ff2_w,
    const float* __restrict__ ff2_b, const float* __restrict__ ln_g,
    const float* __restrict__ ln_b, const float* __restrict__ fc1_w,
    float* __restrict__ table, float* __restrict__ G, float* __restrict__ Z0)
{
    __shared__ float tl[64][32];
    const int v = threadIdx.x;
    float h[32], f[32];
#pragma unroll
    for (int j = 0; j < 32; ++j) { h[j] = embed[v * 32 + j]; f[j] = 0.f; }
    for (int k = 0; k < 64; ++k) {
        float z = ff1_b[k];
#pragma unroll
        for (int j = 0; j < 32; ++j) z += h[j] * ff1_w[k * 32 + j];
        z = fmaxf(z, 0.f);
#pragma unroll
        for (int j = 0; j < 32; ++j) f[j] += z * ff2_w[j * 64 + k];
    }
    float x[32], mu = 0.f;
#pragma unroll
    for (int j = 0; j < 32; ++j) { x[j] = h[j] + f[j] + ff2_b[j]; mu += x[j]; }
    mu *= (1.f / 32.f);
    float var = 0.f;
#pragma unroll
    for (int j = 0; j < 32; ++j) { float d = x[j] - mu; var += d * d; }
    var *= (1.f / 32.f);
    const float inv = rsqrtf(var + 1e-5f);
    float tv[32];
#pragma unroll
    for (int j = 0; j < 32; ++j) {
        tv[j] = ln_g[j] * (x[j] - mu) * inv + ln_b[j];
        tl[v][j] = tv[j];
        table[v * 32 + j] = tv[j];
    }
    __syncthreads();
    for (int u = 0; u < 64; ++u) {
        float acc = 0.f;
#pragma unroll
        for (int j = 0; j < 32; ++j) acc += tv[j] * tl[u][j];
        G[v * 64 + u] = acc;
    }
    for (int i = 0; i < 8; ++i) {
        float acc = 0.f;
#pragma unroll
        for (int j = 0; j < 32; ++j) acc += fc1_w[i * 32 + j] * tv[j];
        Z0[v * 8 + i] = acc;
    }
}

// ---------------------------------------------------------------------------
// Phase B: fused gate + fast-weight scan. One wave per batch row.
// DS pipeline: bpermute issued FIRST each iter (consumer waits lgkmcnt(4),
// never 0); token-indexed rows (Sr/Ga/Gb) prefetched 2 iters ahead, vc 1.5.
// ---------------------------------------------------------------------------
__global__ __launch_bounds__(64) void scan_kernel(
    const int* __restrict__ seq, const float* __restrict__ tableg,
    const float* __restrict__ Gg, const float* __restrict__ Z0g,
    const float* __restrict__ fc1_b, const float* __restrict__ fc2_w,
    const float* __restrict__ fc2_b, const float* __restrict__ out_w,
    const float* __restrict__ out_b, float* __restrict__ out,
    float* __restrict__ wacc)
{
    __shared__ float Gs[4096];
    __shared__ float tabs[2048];
    __shared__ float ctx_s[32];
    const int b = blockIdx.x, tid = threadIdx.x;
    const int i = tid & 7, g = tid >> 3;
    const int l31 = tid & 31;
    const int i4 = i << 2;
    for (int idx = tid; idx < 4096; idx += 64) Gs[idx] = Gg[idx];
    for (int idx = tid; idx < 2048; idx += 64) tabs[idx] = tableg[idx];
    __syncthreads();
    const float4* tab4 = reinterpret_cast<const float4*>(tabs);

    // --- model state ---
    float Zr[8];
#pragma unroll
    for (int r = 0; r < 8; ++r) Zr[r] = Z0g[(8 * g + r) * 8 + i];
    float b1 = fc1_b[i];
    float W2r0 = fc2_w[(4 * g + 0) * 8 + i];
    float W2r1 = fc2_w[(4 * g + 1) * 8 + i];
    float W2r2 = fc2_w[(4 * g + 2) * 8 + i];
    float W2r3 = fc2_w[(4 * g + 3) * 8 + i];
    float4 b2r = reinterpret_cast<const float4*>(fc2_b)[g];

    const float dG = Gs[tid * 65];     // G[v][v] per lane

    const int2* sp2 = reinterpret_cast<const int2*>(seq + b * L_SEQ);
    int2 cbA = sp2[l31];
    int2 cbB = sp2[32 + l31];
    int2 cbC = sp2[64 + l31];

    int k0 = rli(cbA.x, 0), v0t = rli(cbA.y, 0);
    int k1 = rli(cbA.x, 1), v1t = rli(cbA.y, 1);
    int k2 = rli(cbA.x, 2), v2t = rli(cbA.y, 2);

    // --- prologue DS: rows k0,k1,k2 / v0,v1,v2 + two bpermutes ---
    float Sr0 = Gs[k0 * 64 + tid];
    const float4* gp0 = reinterpret_cast<const float4*>(Gs + k0 * 64 + 8 * g);
    float4 Ga0 = gp0[0], Gb0 = gp0[1];
    float4 vc0 = tab4[v0t * 8 + g];
    float Sr1 = Gs[k1 * 64 + tid];
    const float4* gp1 = reinterpret_cast<const float4*>(Gs + k1 * 64 + 8 * g);
    float4 Ga1 = gp1[0], Gb1 = gp1[1];
    float4 vc1 = tab4[v1t * 8 + g];
    float Sr2 = Gs[k2 * 64 + tid];
    const float4* gp2 = reinterpret_cast<const float4*>(Gs + k2 * 64 + 8 * g);
    float4 Ga2 = gp2[0], Gb2 = gp2[1];
    float4 vc2 = tab4[v2t * 8 + g];
    float y0 = bperm_row(k0, i4, sel8d(Zr, k0 & 7));
    float y1 = bperm_row(k1, i4, sel8d(Zr, k1 & 7));

    // --- step 0 (always write) ---
    float es0 = b2r.x - vc0.x, es1 = b2r.y - vc0.y;
    float es2 = b2r.z - vc0.z, es3 = b2r.w - vc0.w;
    {
        const float z1 = y0 + b1;
        const float a  = fmaxf(z1, 0.f);
        float p0 = W2r0 * a, p1 = W2r1 * a, p2 = W2r2 * a, p3 = W2r3 * a;
        redi4(p0, p1, p2, p3);
        const float dp0 = p0 + es0, dp1 = p1 + es1;
        const float dp2 = p2 + es2, dp3 = p3 + es3;
        float q = redg1(fmaf(W2r0, dp0, W2r1 * dp1) + fmaf(W2r2, dp2, W2r3 * dp3));
        const float c = (z1 > 0.f) ? ST_W * q : 0.f;
        const float u0 = ST_W * dp0, u1 = ST_W * dp1;
        const float u2 = ST_W * dp2, u3 = ST_W * dp3;
        W2r0 = fmaf(u0, a, W2r0); W2r1 = fmaf(u1, a, W2r1);
        W2r2 = fmaf(u2, a, W2r2); W2r3 = fmaf(u3, a, W2r3);
        b2r.x += u0; b2r.y += u1; b2r.z += u2; b2r.w += u3;
        Zr[0] = fmaf(c, Ga0.x, Zr[0]); Zr[1] = fmaf(c, Ga0.y, Zr[1]);
        Zr[2] = fmaf(c, Ga0.z, Zr[2]); Zr[3] = fmaf(c, Ga0.w, Zr[3]);
        Zr[4] = fmaf(c, Gb0.x, Zr[4]); Zr[5] = fmaf(c, Gb0.y, Zr[5]);
        Zr[6] = fmaf(c, Gb0.z, Zr[6]); Zr[7] = fmaf(c, Gb0.w, Zr[7]);
        es0 = b2r.x - vc1.x; es1 = b2r.y - vc1.y;
        es2 = b2r.z - vc1.z; es3 = b2r.w - vc1.w;
        // carried forward
        y0 = c;  // reuse slot: c_prev
    }
    float c_prev = y0;
    float yb  = y1 + (b1 - 0.f);          // uses pre-update b1? b1 not yet updated
    b1 += c_prev;                          // b1_0
    float gB1 = rlf(Sr1, k0) + 1.f;

    // --- gate init: st for step 1 ---
    float u  = rlf(dG, k0);                // u_1 = |k0|^2
    float S  = Sr0;                        // S_1
    float tf = 1.f;
    float A1  = rlf(S, k1);
    float G11 = rlf(dG, k1);
    float rr  = (G11 - 16.f + u) - 2.f * A1;
    float st_c = (rr > 0.f) ? ST_W : 0.f;
    float Aprev = A1, Gprev = G11;
    float nwf = 1.f;

    // --- rotate into steady state ---
    int kA = k1, kB = k2;
    float SrA = Sr1, SrB = Sr2;
    float4 GaA = Ga1, GbA = Gb1, GaB = Ga2, GbB = Gb2;
    float4 vcR = vc2;

#pragma unroll 3
    for (int t = 1; t < NSTEP; ++t) {
        // (1) bpermute first: consumer at end of iter waits lgkmcnt(4)
        float ynv = bperm_row(kB, i4, sel8d(Zr, kB & 7));   // Z_{t-1}[k_{t+1}]

        // (2) tokens for step t+2
        const int ts = t & 31;
        if (ts == 0) {
            cbA = cbB; cbB = cbC;
            int c2 = (t >> 5) + 2; if (c2 > 63) c2 = 63;
            cbC = sp2[c2 * 32 + l31];
        }
        const int idx2 = (t + 2) & 31;
        const bool hi2 = (ts >= 30);
        int ka_ = rli(cbA.x, idx2), kb_ = rli(cbB.x, idx2);
        int va_ = rli(cbA.y, idx2), vb_ = rli(cbB.y, idx2);
        const int kn = hi2 ? kb_ : ka_;
        const int vn = hi2 ? vb_ : va_;

        // (3) issue DS for rows k_{t+2}, v_{t+2}
        float SrN = Gs[kn * 64 + tid];
        const float4* gnp = reinterpret_cast<const float4*>(Gs + kn * 64 + 8 * g);
        float4 GaN = gnp[0], GbN = gnp[1];
        float4 vcN = tab4[vn * 8 + g];

        // (4) gate-ahead: st for step t+1 (pure side chain)
        u = fmaf(2.f, Aprev, u) + Gprev;          // u_{t+1}
        S += SrA;                                 // S_{t+1}
        tf += 1.f;
        const float A1n  = rlf(S, kB);
        const float G11n = rlf(dG, kB);
        const float rrn  = fmaf(tf * tf, G11n - 16.f, u) - (tf + tf) * A1n;
        const float stN  = (rrn > 0.f) ? ST_W : 0.f;
        Aprev = A1n; Gprev = G11n;

        // (5) critical path: step t
        const float z1 = fmaf(c_prev, gB1, yb);
        const float a  = fmaxf(z1, 0.f);
        float p0 = W2r0 * a, p1 = W2r1 * a, p2 = W2r2 * a, p3 = W2r3 * a;
        redi4(p0, p1, p2, p3);
        const float dp0 = p0 + es0, dp1 = p1 + es1;
        const float dp2 = p2 + es2, dp3 = p3 + es3;
        float q = redg1(fmaf(W2r0, dp0, W2r1 * dp1) + fmaf(W2r2, dp2, W2r3 * dp3));
        const float c = (z1 > 0.f) ? st_c * q : 0.f;
        nwf += (st_c != 0.f) ? 1.f : 0.f;

        // (6) updates (off critical path)
        const float u0 = st_c * dp0, u1 = st_c * dp1;
        const float u2 = st_c * dp2, u3 = st_c * dp3;
        W2r0 = fmaf(u0, a, W2r0); W2r1 = fmaf(u1, a, W2r1);
        W2r2 = fmaf(u2, a, W2r2); W2r3 = fmaf(u3, a, W2r3);
        b2r.x += u0; b2r.y += u1; b2r.z += u2; b2r.w += u3;
        Zr[0] = fmaf(c, GaA.x, Zr[0]); Zr[1] = fmaf(c, GaA.y, Zr[1]);
        Zr[2] = fmaf(c, GaA.z, Zr[2]); Zr[3] = fmaf(c, GaA.w, Zr[3]);
        Zr[4] = fmaf(c, GbA.x, Zr[4]); Zr[5] = fmaf(c, GbA.y, Zr[5]);
        Zr[6] = fmaf(c, GbA.z, Zr[6]); Zr[7] = fmaf(c, GbA.w, Zr[7]);
        const float ybN = ynv + b1;               // waits lgkmcnt(4)
        b1 += c;
        es0 = b2r.x - vcR.x; es1 = b2r.y - vcR.y; // vcR: issued last iter
        es2 = b2r.z - vcR.z; es3 = b2r.w - vcR.w;
        const float gB1N = rlf(SrB, kA) + 1.f;    // G[k_t][k_{t+1}] (symmetry)

        // (7) rotate
        yb = ybN; gB1 = gB1N; c_prev = c; st_c = stN;
        SrA = SrB; SrB = SrN;
        GaA = GaB; GbA = GbB; GaB = GaN; GbB = GbN;
        vcR = vcN;
        kA = kB; kB = kn;
    }

    // --- query/context ---
    const int tq = seq[b * L_SEQ + (L_SEQ - 1)];
    float yq = bperm_row(tq, i4, sel8d(Zr, tq & 7));
    const float zq = yq + b1;
    const float aq = fmaxf(zq, 0.f);
    float c0 = W2r0 * aq, c1 = W2r1 * aq, c2 = W2r2 * aq, c3 = W2r3 * aq;
    redi4(c0, c1, c2, c3);
    if (i == 0) {
        ctx_s[4 * g + 0] = c0 + b2r.x;
        ctx_s[4 * g + 1] = c1 + b2r.y;
        ctx_s[4 * g + 2] = c2 + b2r.z;
        ctx_s[4 * g + 3] = c3 + b2r.w;
    }
    __syncthreads();

    float acc = out_b[tid];
#pragma unroll
    for (int j = 0; j < 32; ++j) acc += ctx_s[j] * out_w[tid * 32 + j];
    out[b * 64 + tid] = acc;

    if (tid == 0) atomicAdd(wacc, nwf);   // integer-valued: exact
}

__global__ void finalize_kernel(const float* __restrict__ wacc,
                                float* __restrict__ out)
{
    out[16384] = wacc[0] * (1.0f / 524032.0f);   // / (B * n) = 256 * 2047
}

// ---------------------------------------------------------------------------
extern "C" void kernel_launch(void* const* d_in, const int* in_sizes, int n_in,
                              void* d_out, int out_size, void* d_ws, size_t ws_size,
                              hipStream_t stream)
{
    const int*   seq   = (const int*)  d_in[0];
    const float* embed = (const float*)d_in[1];
    const float* ff1_w = (const float*)d_in[2];
    const float* ff1_b = (const float*)d_in[3];
    const float* ff2_w = (const float*)d_in[4];
    const float* ff2_b = (const float*)d_in[5];
    const float* ln_g  = (const float*)d_in[6];
    const float* ln_b  = (const float*)d_in[7];
    const float* fc1_w = (const float*)d_in[8];
    const float* fc1_b = (const float*)d_in[9];
    const float* fc2_w = (const float*)d_in[10];
    const float* fc2_b = (const float*)d_in[11];
    const float* out_w = (const float*)d_in[12];
    const float* out_b = (const float*)d_in[13];

    float* out = (float*)d_out;
    char* ws = (char*)d_ws;
    float* table = (float*)(ws + 0);
    float* G     = (float*)(ws + 8192);
    float* Z0    = (float*)(ws + 24576);
    float* wacc  = (float*)(ws + 26624);

    hipMemsetAsync(wacc, 0, sizeof(float), stream);
    hipLaunchKernelGGL(build_kernel, dim3(1), dim3(64), 0, stream,
                       embed, ff1_w, ff1_b, ff2_w, ff2_b, ln_g, ln_b, fc1_w,
                       table, G, Z0);
    hipLaunchKernelGGL(scan_kernel, dim3(256), dim3(64), 0, stream,
                       seq, table, G, Z0, fc1_b, fc2_w, fc2_b,
                       out_w, out_b, out, wacc);
    hipLaunchKernelGGL(finalize_kernel, dim3(1), dim3(1), 0, stream, wacc, out);
}

// Round 7
// 582.410 us; speedup vs baseline: 1.0852x; 1.0852x over previous
//
#include <hip/hip_runtime.h>

#define L_SEQ 4096
#define NSTEP 2047
#define ST_W  (-0.000625f)   // -LR * (2/H) = -0.01/16

// ws layout (bytes):
//  [0,      8192)   table  64x32 f32
//  [8192,  24576)   G      64x64 f32
//  [24576, 26624)   Z0     64x8  f32
//  [26624, 26628)   wacc   f32
//  [28672, 94208)   flags  256 rows x 64 words (bit ts of word t>>5 = wr_t)

// ---------------------------------------------------------------------------
// Cross-lane reduction helpers (VALU pipe). Layout: i = lane&7, g = lane>>3.
// ---------------------------------------------------------------------------
__device__ __forceinline__ void redi4(float& a, float& b, float& c, float& d) {
    asm volatile(
        "s_nop 1\n\t"
        "v_add_f32_dpp %0, %0, %0 quad_perm:[1,0,3,2] row_mask:0xf bank_mask:0xf bound_ctrl:0\n\t"
        "v_add_f32_dpp %1, %1, %1 quad_perm:[1,0,3,2] row_mask:0xf bank_mask:0xf bound_ctrl:0\n\t"
        "v_add_f32_dpp %2, %2, %2 quad_perm:[1,0,3,2] row_mask:0xf bank_mask:0xf bound_ctrl:0\n\t"
        "v_add_f32_dpp %3, %3, %3 quad_perm:[1,0,3,2] row_mask:0xf bank_mask:0xf bound_ctrl:0\n\t"
        "v_add_f32_dpp %0, %0, %0 quad_perm:[2,3,0,1] row_mask:0xf bank_mask:0xf bound_ctrl:0\n\t"
        "v_add_f32_dpp %1, %1, %1 quad_perm:[2,3,0,1] row_mask:0xf bank_mask:0xf bound_ctrl:0\n\t"
        "v_add_f32_dpp %2, %2, %2 quad_perm:[2,3,0,1] row_mask:0xf bank_mask:0xf bound_ctrl:0\n\t"
        "v_add_f32_dpp %3, %3, %3 quad_perm:[2,3,0,1] row_mask:0xf bank_mask:0xf bound_ctrl:0\n\t"
        "v_add_f32_dpp %0, %0, %0 row_half_mirror row_mask:0xf bank_mask:0xf bound_ctrl:0\n\t"
        "v_add_f32_dpp %1, %1, %1 row_half_mirror row_mask:0xf bank_mask:0xf bound_ctrl:0\n\t"
        "v_add_f32_dpp %2, %2, %2 row_half_mirror row_mask:0xf bank_mask:0xf bound_ctrl:0\n\t"
        "v_add_f32_dpp %3, %3, %3 row_half_mirror row_mask:0xf bank_mask:0xf bound_ctrl:0"
        : "+v"(a), "+v"(b), "+v"(c), "+v"(d));
}

__device__ __forceinline__ float redg1(float x) {
    float t;
    asm volatile(
        "s_nop 1\n\t"
        "v_add_f32_dpp %0, %0, %0 row_ror:8 row_mask:0xf bank_mask:0xf bound_ctrl:0\n\t"
        "s_nop 1\n\t"
        "v_mov_b32 %1, %0\n\t"
        "s_nop 1\n\t"
        "v_permlane16_swap_b32 %1, %0\n\t"
        "s_nop 0\n\t"
        "v_add_f32 %0, %0, %1\n\t"
        "s_nop 1\n\t"
        "v_mov_b32 %1, %0\n\t"
        "s_nop 1\n\t"
        "v_permlane32_swap_b32 %1, %0\n\t"
        "s_nop 0\n\t"
        "v_add_f32 %0, %0, %1"
        : "+v"(x), "=&v"(t));
    return x;
}

// select Z[r] among 8 regs; r wave-uniform SGPR. SALU builds 3 s-pair masks,
// exactly 7 v_cndmask on the VALU.
__device__ __forceinline__ float sel8u(const float* Z, int r) {
    unsigned long long m0 = (r & 1) ? ~0ull : 0ull;
    unsigned long long m1 = (r & 2) ? ~0ull : 0ull;
    unsigned long long m2 = (r & 4) ? ~0ull : 0ull;
    float a0, a1, a2, a3, b0, b1v, res;
    asm("v_cndmask_b32 %0, %1, %2, %3" : "=v"(a0) : "v"(Z[0]), "v"(Z[1]), "s"(m0));
    asm("v_cndmask_b32 %0, %1, %2, %3" : "=v"(a1) : "v"(Z[2]), "v"(Z[3]), "s"(m0));
    asm("v_cndmask_b32 %0, %1, %2, %3" : "=v"(a2) : "v"(Z[4]), "v"(Z[5]), "s"(m0));
    asm("v_cndmask_b32 %0, %1, %2, %3" : "=v"(a3) : "v"(Z[6]), "v"(Z[7]), "s"(m0));
    asm("v_cndmask_b32 %0, %1, %2, %3" : "=v"(b0)  : "v"(a0), "v"(a1), "s"(m1));
    asm("v_cndmask_b32 %0, %1, %2, %3" : "=v"(b1v) : "v"(a2), "v"(a3), "s"(m1));
    asm("v_cndmask_b32 %0, %1, %2, %3" : "=v"(res) : "v"(b0), "v"(b1v), "s"(m2));
    return res;
}

__device__ __forceinline__ float bperm_row(int tok, int i4, float v) {
    int addr = ((tok & 56) << 2) | i4;
    return __int_as_float(__builtin_amdgcn_ds_bpermute(addr, __float_as_int(v)));
}

__device__ __forceinline__ int rli(int x, int l) {
    return __builtin_amdgcn_readlane(x, l);
}

// ---------------------------------------------------------------------------
// Phase A: table[v] = LN(e_v + MLP(e_v)); G = table·tableᵀ; Z0 = fc1_w·tableᵀ
// ---------------------------------------------------------------------------
__global__ __launch_bounds__(64) void build_kernel(
    const float* __restrict__ embed, const float* __restrict__ ff1_w,
    const float* __restrict__ ff1_b, const float* __restrict__ ff2_w,
    const float* __restrict__ ff2_b, const float* __restrict__ ln_g,
    const float* __restrict__ ln_b, const float* __restrict__ fc1_w,
    float* __restrict__ table, float* __restrict__ G, float* __restrict__ Z0)
{
    __shared__ float tl[64][32];
    const int v = threadIdx.x;
    float h[32], f[32];
#pragma unroll
    for (int j = 0; j < 32; ++j) { h[j] = embed[v * 32 + j]; f[j] = 0.f; }
    for (int k = 0; k < 64; ++k) {
        float z = ff1_b[k];
#pragma unroll
        for (int j = 0; j < 32; ++j) z += h[j] * ff1_w[k * 32 + j];
        z = fmaxf(z, 0.f);
#pragma unroll
        for (int j = 0; j < 32; ++j) f[j] += z * ff2_w[j * 64 + k];
    }
    float x[32], mu = 0.f;
#pragma unroll
    for (int j = 0; j < 32; ++j) { x[j] = h[j] + f[j] + ff2_b[j]; mu += x[j]; }
    mu *= (1.f / 32.f);
    float var = 0.f;
#pragma unroll
    for (int j = 0; j < 32; ++j) { float d = x[j] - mu; var += d * d; }
    var *= (1.f / 32.f);
    const float inv = rsqrtf(var + 1e-5f);
    float tv[32];
#pragma unroll
    for (int j = 0; j < 32; ++j) {
        tv[j] = ln_g[j] * (x[j] - mu) * inv + ln_b[j];
        tl[v][j] = tv[j];
        table[v * 32 + j] = tv[j];
    }
    __syncthreads();
    for (int u = 0; u < 64; ++u) {
        float acc = 0.f;
#pragma unroll
        for (int j = 0; j < 32; ++j) acc += tv[j] * tl[u][j];
        G[v * 64 + u] = acc;
    }
    for (int i = 0; i < 8; ++i) {
        float acc = 0.f;
#pragma unroll
        for (int j = 0; j < 32; ++j) acc += fc1_w[i * 32 + j] * tv[j];
        Z0[v * 8 + i] = acc;
    }
}

// ---------------------------------------------------------------------------
// Phase B1: PARALLEL write-gate kernel. One 256-thread block per batch row.
// A_t = Σ_{s<t} G[k_s][k_t] via 32-step chunk prefix; u_t = prefix of
// w_s = 2A_s + G_ss (Hillis-Steele). wr_t = (t==0) || (u - 2tA + t²(Gtt-16) > 0)
// ---------------------------------------------------------------------------
__global__ __launch_bounds__(256) void flags_kernel(
    const int* __restrict__ seq, const float* __restrict__ Gg,
    unsigned int* __restrict__ flags, float* __restrict__ wacc)
{
    __shared__ float Gs[4096];
    __shared__ float P[64][64];
    __shared__ int   kt[2048];
    __shared__ float Aa[2048];
    __shared__ float Ws[2048];
    __shared__ float red[256];
    const int tid = threadIdx.x, b = blockIdx.x;
    for (int idx = tid; idx < 4096; idx += 256) Gs[idx] = Gg[idx];
    const int2* sp2 = reinterpret_cast<const int2*>(seq + b * L_SEQ);
    for (int j = tid; j < 2048; j += 256) kt[j] = sp2[j].x;
    __syncthreads();

    // chunk row-sums: P[c][u] = Σ_{s in chunk c} G[k_s][u]
    for (int idx = tid; idx < 4096; idx += 256) {
        const int c = idx >> 6, u = idx & 63;
        const int base = c * 32;
        float s = 0.f;
#pragma unroll 4
        for (int j = 0; j < 32; ++j) s += Gs[kt[base + j] * 64 + u];
        P[c][u] = s;
    }
    __syncthreads();
    // exclusive prefix over chunks, per u
    if (tid < 64) {
        float acc = 0.f;
        for (int c = 0; c < 64; ++c) { float p = P[c][tid]; P[c][tid] = acc; acc += p; }
    }
    __syncthreads();
    // A_t and w_t
    for (int t = tid; t < NSTEP; t += 256) {
        const int c = t >> 5, base = c << 5;
        const int ktt = kt[t];
        float a = P[c][ktt];
        for (int s = base; s < t; ++s) a += Gs[kt[s] * 64 + ktt];
        Aa[t] = a;
        Ws[t] = 2.f * a + Gs[ktt * 65];
    }
    __syncthreads();
    // exclusive prefix sum of Ws over 2047 entries (8 per thread + block scan)
    float loc[8], tot = 0.f;
    const int base8 = tid * 8;
#pragma unroll
    for (int j = 0; j < 8; ++j) {
        float v = (base8 + j < NSTEP) ? Ws[base8 + j] : 0.f;
        loc[j] = tot; tot += v;
    }
    red[tid] = tot;
    __syncthreads();
    float run = tot;
    for (int off = 1; off < 256; off <<= 1) {
        float add = (tid >= off) ? red[tid - off] : 0.f;
        __syncthreads();
        run += add; red[tid] = run;
        __syncthreads();
    }
    const float excl = run - tot;
    __syncthreads();
#pragma unroll
    for (int j = 0; j < 8; ++j) {
        const int t = base8 + j;
        if (t < NSTEP) {
            const float u_t = excl + loc[j];
            const float tf = (float)t;
            const int ktt = kt[t];
            const float r = fmaf(tf * tf, Gs[ktt * 65] - 16.f, u_t)
                            - 2.f * tf * Aa[t];
            Ws[t] = (t == 0 || r > 0.f) ? 1.f : 0.f;
        }
    }
    __syncthreads();
    int cnt = 0;
    if (tid < 64) {
        unsigned int w = 0;
        for (int j = 0; j < 32; ++j) {
            const int t = tid * 32 + j;
            if (t < NSTEP && Ws[t] != 0.f) w |= 1u << j;
        }
        flags[b * 64 + tid] = w;
        cnt = __popc(w);
    }
    red[tid] = (float)cnt;
    __syncthreads();
    if (tid == 0) {
        float s = 0.f;
        for (int j = 0; j < 64; ++j) s += red[j];
        atomicAdd(wacc, s);
    }
}

// ---------------------------------------------------------------------------
// Phase B2: fast-weight scan, gate-free (flags precomputed). One wave/row.
// Lane (i=tid&7, g=tid>>3): Zr[r]=Z[8g+r][i], W2[4g+c][i], b2[4g+c].
// 5 DS ops/step, all ≥1 step of slack; ~80 VALU/step.
// ---------------------------------------------------------------------------
__global__ __launch_bounds__(64) void scan_kernel(
    const int* __restrict__ seq, const float* __restrict__ tableg,
    const float* __restrict__ Gg, const float* __restrict__ Z0g,
    const float* __restrict__ fc1_b, const float* __restrict__ fc2_w,
    const float* __restrict__ fc2_b, const float* __restrict__ out_w,
    const float* __restrict__ out_b, const unsigned int* __restrict__ flags,
    float* __restrict__ out)
{
    __shared__ float Gs[4096];
    __shared__ float tabs[2048];
    __shared__ float ctx_s[32];
    const int b = blockIdx.x, tid = threadIdx.x;
    const int i = tid & 7, g = tid >> 3;
    const int l31 = tid & 31;
    const int i4 = i << 2;
    for (int idx = tid; idx < 4096; idx += 64) Gs[idx] = Gg[idx];
    for (int idx = tid; idx < 2048; idx += 64) tabs[idx] = tableg[idx];
    __syncthreads();
    const float4* tab4 = reinterpret_cast<const float4*>(tabs);

    // --- state ---
    float Zr[8];
#pragma unroll
    for (int r = 0; r < 8; ++r) Zr[r] = Z0g[(8 * g + r) * 8 + i];
    float b1 = fc1_b[i];
    float W2r0 = fc2_w[(4 * g + 0) * 8 + i];
    float W2r1 = fc2_w[(4 * g + 1) * 8 + i];
    float W2r2 = fc2_w[(4 * g + 2) * 8 + i];
    float W2r3 = fc2_w[(4 * g + 3) * 8 + i];
    float4 b2r = reinterpret_cast<const float4*>(fc2_b)[g];

    const int2* sp2 = reinterpret_cast<const int2*>(seq + b * L_SEQ);
    const unsigned int fwv = flags[b * 64 + tid];   // lane l holds word l

    int2 cbA = sp2[l31];
    int2 cbB = sp2[32 + l31];
    int2 cbC = sp2[64 + l31];

    int kc  = rli(cbA.x, 0);
    int vct = rli(cbA.y, 0);
    int kn1 = rli(cbA.x, 1);
    int vn1 = rli(cbA.y, 1);

    // --- prologue (one-time latency) ---
    const float4* gp0 = reinterpret_cast<const float4*>(Gs + kc * 64 + 8 * g);
    float4 GaC = gp0[0], GbC = gp0[1];
    const float4* gp1 = reinterpret_cast<const float4*>(Gs + kn1 * 64 + 8 * g);
    float4 GaN1 = gp1[0], GbN1 = gp1[1];
    float4 vcC  = tab4[vct * 8 + g];
    float4 vcN1 = tab4[vn1 * 8 + g];
    float gbIn  = Gs[kc * 64 + kn1];                 // G[k0][k1]
    float yb = bperm_row(kc, i4, sel8u(Zr, kc & 7)) + b1;
    float es0 = b2r.x - vcC.x, es1 = b2r.y - vcC.y;
    float es2 = b2r.z - vcC.z, es3 = b2r.w - vcC.w;
    float c_prev = 0.f, gB1c = 0.f;
    unsigned int fw = 0;

#pragma unroll 3
    for (int t = 0; t < NSTEP; ++t) {
        const int ts = t & 31;
        if (ts == 0) {
            fw = (unsigned int)rli((int)fwv, t >> 5);
            if (t) {
                cbA = cbB; cbB = cbC;
                int c2 = (t >> 5) + 2; if (c2 > 63) c2 = 63;
                cbC = sp2[c2 * 32 + l31];
            }
        }
        const float st = ((fw >> ts) & 1u) ? ST_W : 0.f;   // SALU + 1 select

        // tokens for t+2
        const int idx2 = (t + 2) & 31;
        const bool hi2 = (ts >= 30);
        int cx = hi2 ? cbB.x : cbA.x;
        int cy = hi2 ? cbB.y : cbA.y;
        const int kn2 = rli(cx, idx2);
        const int vn2 = rli(cy, idx2);

        // bperm for step t+1 (reads Z_{t-1}; corrected via gB1c next step)
        float ynv = bperm_row(kn1, i4, sel8u(Zr, kn1 & 7));

        // DS prefetch for t+2 (2 steps of slack)
        const float4* gpn = reinterpret_cast<const float4*>(Gs + kn2 * 64 + 8 * g);
        float4 GaN = gpn[0], GbN = gpn[1];
        float4 vcN = tab4[vn2 * 8 + g];
        float gbNew = Gs[kn1 * 64 + kn2];            // G[k_{t+1}][k_{t+2}]

        // --- critical path (step t) ---
        const float z1 = fmaf(c_prev, gB1c, yb);
        const float a  = fmaxf(z1, 0.f);
        float p0 = W2r0 * a, p1 = W2r1 * a, p2 = W2r2 * a, p3 = W2r3 * a;
        redi4(p0, p1, p2, p3);
        const float dp0 = p0 + es0, dp1 = p1 + es1;
        const float dp2 = p2 + es2, dp3 = p3 + es3;
        float q = redg1(fmaf(W2r0, dp0, W2r1 * dp1) + fmaf(W2r2, dp2, W2r3 * dp3));
        const float c = (z1 > 0.f) ? st * q : 0.f;

        // --- updates (off critical path) ---
        const float u0 = st * dp0, u1 = st * dp1;
        const float u2 = st * dp2, u3 = st * dp3;
        W2r0 = fmaf(u0, a, W2r0); W2r1 = fmaf(u1, a, W2r1);
        W2r2 = fmaf(u2, a, W2r2); W2r3 = fmaf(u3, a, W2r3);
        b2r.x += u0; b2r.y += u1; b2r.z += u2; b2r.w += u3;
        Zr[0] = fmaf(c, GaC.x, Zr[0]); Zr[1] = fmaf(c, GaC.y, Zr[1]);
        Zr[2] = fmaf(c, GaC.z, Zr[2]); Zr[3] = fmaf(c, GaC.w, Zr[3]);
        Zr[4] = fmaf(c, GbC.x, Zr[4]); Zr[5] = fmaf(c, GbC.y, Zr[5]);
        Zr[6] = fmaf(c, GbC.z, Zr[6]); Zr[7] = fmaf(c, GbC.w, Zr[7]);
        const float ybN = ynv + b1;                  // pre-update b1
        b1 += c;
        es0 = b2r.x - vcN1.x; es1 = b2r.y - vcN1.y;  // es for step t+1
        es2 = b2r.z - vcN1.z; es3 = b2r.w - vcN1.w;

        // --- rotate ---
        yb = ybN; c_prev = c; gB1c = gbIn + 1.f; gbIn = gbNew;
        GaC = GaN1; GbC = GbN1; GaN1 = GaN; GbN1 = GbN;
        vcN1 = vcN;
        kn1 = kn2;
    }

    // --- query/context ---
    const int tq = seq[b * L_SEQ + (L_SEQ - 1)];
    float yq = bperm_row(tq, i4, sel8u(Zr, tq & 7));
    const float zq = yq + b1;
    const float aq = fmaxf(zq, 0.f);
    float c0 = W2r0 * aq, c1 = W2r1 * aq, c2 = W2r2 * aq, c3 = W2r3 * aq;
    redi4(c0, c1, c2, c3);
    if (i == 0) {
        ctx_s[4 * g + 0] = c0 + b2r.x;
        ctx_s[4 * g + 1] = c1 + b2r.y;
        ctx_s[4 * g + 2] = c2 + b2r.z;
        ctx_s[4 * g + 3] = c3 + b2r.w;
    }
    __syncthreads();

    float acc = out_b[tid];
#pragma unroll
    for (int j = 0; j < 32; ++j) acc += ctx_s[j] * out_w[tid * 32 + j];
    out[b * 64 + tid] = acc;
}

__global__ void finalize_kernel(const float* __restrict__ wacc,
                                float* __restrict__ out)
{
    out[16384] = wacc[0] * (1.0f / 524032.0f);   // / (B * n) = 256 * 2047
}

// ---------------------------------------------------------------------------
extern "C" void kernel_launch(void* const* d_in, const int* in_sizes, int n_in,
                              void* d_out, int out_size, void* d_ws, size_t ws_size,
                              hipStream_t stream)
{
    const int*   seq   = (const int*)  d_in[0];
    const float* embed = (const float*)d_in[1];
    const float* ff1_w = (const float*)d_in[2];
    const float* ff1_b = (const float*)d_in[3];
    const float* ff2_w = (const float*)d_in[4];
    const float* ff2_b = (const float*)d_in[5];
    const float* ln_g  = (const float*)d_in[6];
    const float* ln_b  = (const float*)d_in[7];
    const float* fc1_w = (const float*)d_in[8];
    const float* fc1_b = (const float*)d_in[9];
    const float* fc2_w = (const float*)d_in[10];
    const float* fc2_b = (const float*)d_in[11];
    const float* out_w = (const float*)d_in[12];
    const float* out_b = (const float*)d_in[13];

    float* out = (float*)d_out;
    char* ws = (char*)d_ws;
    float*        table = (float*)(ws + 0);
    float*        G     = (float*)(ws + 8192);
    float*        Z0    = (float*)(ws + 24576);
    float*        wacc  = (float*)(ws + 26624);
    unsigned int* flags = (unsigned int*)(ws + 28672);

    hipMemsetAsync(wacc, 0, sizeof(float), stream);
    hipLaunchKernelGGL(build_kernel, dim3(1), dim3(64), 0, stream,
                       embed, ff1_w, ff1_b, ff2_w, ff2_b, ln_g, ln_b, fc1_w,
                       table, G, Z0);
    hipLaunchKernelGGL(flags_kernel, dim3(256), dim3(256), 0, stream,
                       seq, G, flags, wacc);
    hipLaunchKernelGGL(scan_kernel, dim3(256), dim3(64), 0, stream,
                       seq, table, G, Z0, fc1_b, fc2_w, fc2_b,
                       out_w, out_b, flags, out);
    hipLaunchKernelGGL(finalize_kernel, dim3(1), dim3(1), 0, stream, wacc, out);
}